// Round 1
// 1062.166 us; speedup vs baseline: 1.2552x; 1.2552x over previous
//
#include <hip/hip_runtime.h>

#define B_ 8
#define S_ 2048
#define DIM_ 2048
#define HD_ 128

typedef __attribute__((ext_vector_type(2))) float f32x2;
typedef __attribute__((ext_vector_type(4))) float f32x4;

// ---------------------------------------------------------------------------
// packed-fp32 helpers (v_pk_* = 2 fp32 ops per instruction; required to reach
// the 157 TF fp32 rate — scalar v_fma_f32 tops out at half)
// ---------------------------------------------------------------------------
__device__ __forceinline__ void pkfma(f32x2& d, f32x2 a, f32x2 b) {
    asm("v_pk_fma_f32 %0, %1, %2, %0" : "+v"(d) : "v"(a), "v"(b));
}
__device__ __forceinline__ void pkmul(f32x2& d, f32x2 a, f32x2 b) {
    asm("v_pk_mul_f32 %0, %1, %2" : "=v"(d) : "v"(a), "v"(b));
}
__device__ __forceinline__ f32x2 pkadd(f32x2 a, f32x2 b) {
    f32x2 d;
    asm("v_pk_add_f32 %0, %1, %2" : "=v"(d) : "v"(a), "v"(b));
    return d;
}

// ---------------------------------------------------------------------------
// all-VALU 8-lane butterfly reduction via DPP (no LDS pipe on critical path):
// quad_perm swap-1 (0xB1), quad_perm swap-2 (0x4E), row_half_mirror (0x141;
// lane i reads i^7 within each 8-lane half — after the two quad levels the
// quad sums are quad-uniform, so half-mirror fetches the other quad's sum).
// ---------------------------------------------------------------------------
__device__ __forceinline__ float xadd1(float x) {
    int o = __builtin_amdgcn_update_dpp(0, __float_as_int(x), 0xB1, 0xF, 0xF, true);
    return x + __int_as_float(o);
}
__device__ __forceinline__ float xadd2(float x) {
    int o = __builtin_amdgcn_update_dpp(0, __float_as_int(x), 0x4E, 0xF, 0xF, true);
    return x + __int_as_float(o);
}
__device__ __forceinline__ float xaddh(float x) {
    int o = __builtin_amdgcn_update_dpp(0, __float_as_int(x), 0x141, 0xF, 0xF, true);
    return x + __int_as_float(o);
}

// ---------------------------------------------------------------------------
// Projection GEMM: qkv[s][b][j*128+n] = x[(b,s),:] @ W_j + bias_j
// ---------------------------------------------------------------------------
__global__ __launch_bounds__(256) void proj_kernel(
    const float* __restrict__ x,
    const float* __restrict__ Wq, const float* __restrict__ bq,
    const float* __restrict__ Wk, const float* __restrict__ bk,
    const float* __restrict__ Wv, const float* __restrict__ bv,
    float* __restrict__ qkv)
{
    __shared__ __align__(16) float As[32][132];  // [k][m], padded
    __shared__ __align__(16) float Bs[32][132];  // [k][n], padded

    const int jsel = blockIdx.y;
    const float* Wj   = (jsel == 0) ? Wq : (jsel == 1) ? Wk : Wv;
    const float* bias = (jsel == 0) ? bq : (jsel == 1) ? bk : bv;

    const int m0 = blockIdx.x * 128;
    const int t  = threadIdx.x;
    const int tx = t & 15;
    const int ty = t >> 4;

    float acc[8][8];
    #pragma unroll
    for (int i = 0; i < 8; ++i)
        #pragma unroll
        for (int j = 0; j < 8; ++j) acc[i][j] = 0.f;

    for (int k0 = 0; k0 < DIM_; k0 += 32) {
        #pragma unroll
        for (int p = 0; p < 4; ++p) {
            int slot = t + p * 256;
            int row  = slot >> 3;
            int c4   = slot & 7;
            float4 v = *(const float4*)&x[(size_t)(m0 + row) * DIM_ + k0 + c4 * 4];
            As[c4 * 4 + 0][row] = v.x;
            As[c4 * 4 + 1][row] = v.y;
            As[c4 * 4 + 2][row] = v.z;
            As[c4 * 4 + 3][row] = v.w;
        }
        #pragma unroll
        for (int p = 0; p < 4; ++p) {
            int slot = t + p * 256;
            int kr   = slot >> 5;
            int n4   = slot & 31;
            *(float4*)&Bs[kr][n4 * 4] =
                *(const float4*)&Wj[(size_t)(k0 + kr) * HD_ + n4 * 4];
        }
        __syncthreads();

        #pragma unroll 4
        for (int kk = 0; kk < 32; ++kk) {
            float a[8], b[8];
            *(float4*)&a[0] = *(const float4*)&As[kk][ty * 8];
            *(float4*)&a[4] = *(const float4*)&As[kk][ty * 8 + 4];
            *(float4*)&b[0] = *(const float4*)&Bs[kk][tx * 8];
            *(float4*)&b[4] = *(const float4*)&Bs[kk][tx * 8 + 4];
            #pragma unroll
            for (int i = 0; i < 8; ++i)
                #pragma unroll
                for (int j = 0; j < 8; ++j)
                    acc[i][j] = fmaf(a[i], b[j], acc[i][j]);
        }
        __syncthreads();
    }

    #pragma unroll
    for (int i = 0; i < 8; ++i) {
        int m = m0 + ty * 8 + i;
        int bb = m >> 11;
        int ss = m & 2047;
        size_t base = ((size_t)ss * B_ + bb) * 384 + jsel * 128 + tx * 8;
        #pragma unroll
        for (int j = 0; j < 8; ++j)
            qkv[base + j] = acc[i][j] + bias[tx * 8 + j];
    }
}

// ---------------------------------------------------------------------------
// Row-parallel sequential scan.
// One wave owns 8 rows of one batch (row = t>>3, 16-col chunk = t&7).
//
// This round: the entire step loop's memory traffic is inline asm with
// HAND-COUNTED s_waitcnt vmcnt(N) (HipKittens T3/T4 discipline). Rationale:
// previous version had VGPR_Count=88 — the compiler never materialized the
// 4-deep register pipeline (needs ~150 VGPRs), so every step ate L2 latency
// on the critical path (700 cy/step measured). asm loads cannot be sunk or
// spilled, and counted waits (never vmcnt(0)) keep 3 slots + stores in
// flight across steps. sched_barrier(0) after each wait stops the scheduler
// from hoisting register-only consumers above the waitcnt (rule #18).
// Shuffle reduction replaced by DPP butterfly (zero LDS ops in the loop);
// dot products / w-update use v_pk_fma_f32 (half the VALU issue).
//
// vmcnt ledger (9 loads per LOADSLOT, 1 store per step-region; in-order
// retirement): region = [STEP(wait) ; LOADSLOT ; YST]. Newer-than-slot-S ops
// at its wait: peel 27/28/29/30, steady 31 (= 1 st + 9 L + 1 st + 9 L + 1 st
// + 9 L + 1 st), tail 31/22/13/4.
// ---------------------------------------------------------------------------
__global__ __launch_bounds__(64) void scan_kernel(
    const float* __restrict__ qkv,   // [S][B][384]
    const float* __restrict__ state, // [B][128][128]
    const float* __restrict__ lrp,
    float* __restrict__ ys,          // [S][B][128]
    float* __restrict__ Wf)          // [B][128][128]
{
    const int b    = blockIdx.x & 7;    // batch -> XCD b (L2 locality)
    const int g    = blockIdx.x >> 3;   // row group 0..15
    const int t    = threadIdx.x;
    const int row  = t >> 3;            // 0..7
    const int ch   = t & 7;             // col chunk (16 cols)
    const int grow = g * 8 + row;       // global row 0..127

    const float plr = lrp[0];
    const float nlr = -plr;

    // pipeline registers: 4 slots x (Q 16 + K 16 + V 1) + w 16  ~= 150 VGPR
    f32x4 Qs0a, Qs0b, Qs0c, Qs0d, Ks0a, Ks0b, Ks0c, Ks0d;
    f32x4 Qs1a, Qs1b, Qs1c, Qs1d, Ks1a, Ks1b, Ks1c, Ks1d;
    f32x4 Qs2a, Qs2b, Qs2c, Qs2d, Ks2a, Ks2b, Ks2c, Ks2d;
    f32x4 Qs3a, Qs3b, Qs3c, Qs3d, Ks3a, Ks3b, Ks3c, Ks3d;
    float Vs0, Vs1, Vs2, Vs3;
    float ypcur;

    unsigned off  = (unsigned)((b * 384 + ch * 16) * 4);          // Q/K base, +12288/step-slot
    unsigned offV = (unsigned)((b * 384 + 256 + grow) * 4);       // V addr,   +12288/step-slot
    unsigned offY = (unsigned)((b * HD_ + grow) * 4);             // y store,  +4096/step
    unsigned offW = (unsigned)(((b * HD_ + grow) * HD_ + ch * 16) * 4);

    // w load via asm too, so the compiler tracks ZERO vector loads and never
    // injects its own vmcnt(0) drain inside the loop.
    f32x4 wa, wb, wc, wd;
    asm volatile("global_load_dwordx4 %0, %1, %2"           : "=v"(wa) : "v"(offW), "s"(state));
    asm volatile("global_load_dwordx4 %0, %1, %2 offset:16" : "=v"(wb) : "v"(offW), "s"(state));
    asm volatile("global_load_dwordx4 %0, %1, %2 offset:32" : "=v"(wc) : "v"(offW), "s"(state));
    asm volatile("global_load_dwordx4 %0, %1, %2 offset:48" : "=v"(wd) : "v"(offW), "s"(state));

#define LOADSLOT(S) do {                                                                            \
        asm volatile("global_load_dwordx4 %0, %1, %2"            : "=v"(Qs##S##a) : "v"(off),  "s"(qkv)); \
        asm volatile("global_load_dwordx4 %0, %1, %2 offset:16"  : "=v"(Qs##S##b) : "v"(off),  "s"(qkv)); \
        asm volatile("global_load_dwordx4 %0, %1, %2 offset:32"  : "=v"(Qs##S##c) : "v"(off),  "s"(qkv)); \
        asm volatile("global_load_dwordx4 %0, %1, %2 offset:48"  : "=v"(Qs##S##d) : "v"(off),  "s"(qkv)); \
        asm volatile("global_load_dwordx4 %0, %1, %2 offset:512" : "=v"(Ks##S##a) : "v"(off),  "s"(qkv)); \
        asm volatile("global_load_dwordx4 %0, %1, %2 offset:528" : "=v"(Ks##S##b) : "v"(off),  "s"(qkv)); \
        asm volatile("global_load_dwordx4 %0, %1, %2 offset:544" : "=v"(Ks##S##c) : "v"(off),  "s"(qkv)); \
        asm volatile("global_load_dwordx4 %0, %1, %2 offset:560" : "=v"(Ks##S##d) : "v"(off),  "s"(qkv)); \
        asm volatile("global_load_dword %0, %1, %2"              : "=v"(Vs##S)    : "v"(offV), "s"(qkv)); \
        off  += 12288u;                                                                             \
        offV += 12288u;                                                                             \
    } while (0)

    // issue the 4-slot prefetch BEFORE waiting on w (w-wait overlaps pipeline fill)
    LOADSLOT(0);
    LOADSLOT(1);
    LOADSLOT(2);
    LOADSLOT(3);

    asm volatile("s_waitcnt vmcnt(36)");     // 4 w-loads oldest of 40 in flight
    __builtin_amdgcn_sched_barrier(0);
    f32x2 w01 = wa.xy, w23 = wa.zw, w45 = wb.xy, w67 = wb.zw;
    f32x2 w89 = wc.xy, wab = wc.zw, wcd = wd.xy, wef = wd.zw;

#define STEP(S, WCNT) do {                                                      \
        asm volatile("s_waitcnt vmcnt(" #WCNT ")");                             \
        __builtin_amdgcn_sched_barrier(0);                                      \
        f32x2 ea, eb, ec, ed, ya, yb, yc, yd;                                   \
        pkmul(ea, w01, Ks##S##a.xy); pkmul(eb, w23, Ks##S##a.zw);               \
        pkmul(ec, w45, Ks##S##b.xy); pkmul(ed, w67, Ks##S##b.zw);               \
        pkfma(ea, w89, Ks##S##c.xy); pkfma(eb, wab, Ks##S##c.zw);               \
        pkfma(ec, wcd, Ks##S##d.xy); pkfma(ed, wef, Ks##S##d.zw);               \
        float lv = plr * Vs##S;              /* off critical path */            \
        f32x2 es = pkadd(pkadd(ea, eb), pkadd(ec, ed));                         \
        float ep = es.x + es.y;                                                 \
        ep = xadd1(ep); ep = xadd2(ep); ep = xaddh(ep);                         \
        float c = fmaf(nlr, ep, lv);         /* c = -lr*(ep - v) */             \
        f32x2 c2; c2.x = c; c2.y = c;                                           \
        pkmul(ya, w01, Qs##S##a.xy); pkmul(yb, w23, Qs##S##a.zw);               \
        pkmul(yc, w45, Qs##S##b.xy); pkmul(yd, w67, Qs##S##b.zw);               \
        pkfma(ya, w89, Qs##S##c.xy); pkfma(yb, wab, Qs##S##c.zw);               \
        pkfma(yc, wcd, Qs##S##d.xy); pkfma(yd, wef, Qs##S##d.zw);               \
        pkfma(w01, c2, Ks##S##a.xy); pkfma(w23, c2, Ks##S##a.zw);               \
        pkfma(w45, c2, Ks##S##b.xy); pkfma(w67, c2, Ks##S##b.zw);               \
        pkfma(w89, c2, Ks##S##c.xy); pkfma(wab, c2, Ks##S##c.zw);               \
        pkfma(wcd, c2, Ks##S##d.xy); pkfma(wef, c2, Ks##S##d.zw);               \
        f32x2 ysum = pkadd(pkadd(ya, yb), pkadd(yc, yd));                       \
        float yp = ysum.x + ysum.y;                                             \
        yp = xadd1(yp); yp = xadd2(yp); yp = xaddh(yp);                         \
        ypcur = yp;                                                             \
    } while (0)

#define YST() do {                                                              \
        if (ch == 0)                                                            \
            asm volatile("global_store_dword %0, %1, %2"                        \
                         :: "v"(offY), "v"(ypcur), "s"(ys));                    \
        offY += 4096u;                                                          \
    } while (0)

    // ---- peel: steps 0..3 (pipeline not yet joined by stores) ----
    STEP(0, 27); LOADSLOT(0); YST();
    STEP(1, 28); LOADSLOT(1); YST();
    STEP(2, 29); LOADSLOT(2); YST();
    STEP(3, 30); LOADSLOT(3); YST();

    // ---- steady state: steps 4 .. S_-5, loads run 4 slots ahead ----
    #pragma unroll 1
    for (int s = 4; s < S_ - 4; s += 4) {
        STEP(0, 31); LOADSLOT(0); YST();
        STEP(1, 31); LOADSLOT(1); YST();
        STEP(2, 31); LOADSLOT(2); YST();
        STEP(3, 31); LOADSLOT(3); YST();
    }

    // ---- tail: steps S_-4 .. S_-1, drain (never vmcnt(0) until here) ----
    STEP(0, 31); YST();
    STEP(1, 22); YST();
    STEP(2, 13); YST();
    STEP(3, 4);  YST();

#undef LOADSLOT
#undef STEP
#undef YST

    {
        float* wdst = Wf + ((size_t)b * HD_ + grow) * HD_ + ch * 16;
        f32x4 o0, o1, o2, o3;
        o0.xy = w01; o0.zw = w23;
        o1.xy = w45; o1.zw = w67;
        o2.xy = w89; o2.zw = wab;
        o3.xy = wcd; o3.zw = wef;
        *(f32x4*)&wdst[0]  = o0;
        *(f32x4*)&wdst[4]  = o1;
        *(f32x4*)&wdst[8]  = o2;
        *(f32x4*)&wdst[12] = o3;
    }
}

// ---------------------------------------------------------------------------
// Output projection: out[(b,s), n] = ys[s][b][:] @ Wo + bo
// ---------------------------------------------------------------------------
__global__ __launch_bounds__(256) void outproj_kernel(
    const float* __restrict__ ys,   // [S][B][128]
    const float* __restrict__ Wo,   // [128][2048]
    const float* __restrict__ bo,   // [2048]
    float* __restrict__ out)        // [B*S][2048]
{
    __shared__ __align__(16) float As[64][132];  // [k][m]
    __shared__ __align__(16) float Bs[64][132];  // [k][n]

    const int m0 = blockIdx.x * 128;
    const int n0 = blockIdx.y * 128;
    const int bb = m0 >> 11;
    const int s0 = m0 & 2047;
    const int t  = threadIdx.x;
    const int tx = t & 15;
    const int ty = t >> 4;

    float acc[8][8];
    #pragma unroll
    for (int i = 0; i < 8; ++i)
        #pragma unroll
        for (int j = 0; j < 8; ++j) acc[i][j] = 0.f;

    for (int k0 = 0; k0 < HD_; k0 += 64) {
        #pragma unroll
        for (int p = 0; p < 8; ++p) {
            int slot = t + p * 256;
            int row  = slot >> 4;
            int c4   = slot & 15;
            float4 v = *(const float4*)&ys[((size_t)(s0 + row) * B_ + bb) * HD_ + k0 + c4 * 4];
            As[c4 * 4 + 0][row] = v.x;
            As[c4 * 4 + 1][row] = v.y;
            As[c4 * 4 + 2][row] = v.z;
            As[c4 * 4 + 3][row] = v.w;
        }
        #pragma unroll
        for (int p = 0; p < 8; ++p) {
            int slot = t + p * 256;
            int kr   = slot >> 5;
            int n4   = slot & 31;
            *(float4*)&Bs[kr][n4 * 4] =
                *(const float4*)&Wo[(size_t)(k0 + kr) * DIM_ + n0 + n4 * 4];
        }
        __syncthreads();

        #pragma unroll 4
        for (int kk = 0; kk < 64; ++kk) {
            float a[8], bfr[8];
            *(float4*)&a[0]   = *(const float4*)&As[kk][ty * 8];
            *(float4*)&a[4]   = *(const float4*)&As[kk][ty * 8 + 4];
            *(float4*)&bfr[0] = *(const float4*)&Bs[kk][tx * 8];
            *(float4*)&bfr[4] = *(const float4*)&Bs[kk][tx * 8 + 4];
            #pragma unroll
            for (int i = 0; i < 8; ++i)
                #pragma unroll
                for (int j = 0; j < 8; ++j)
                    acc[i][j] = fmaf(a[i], bfr[j], acc[i][j]);
        }
        __syncthreads();
    }

    #pragma unroll
    for (int i = 0; i < 8; ++i) {
        size_t m = m0 + ty * 8 + i;
        #pragma unroll
        for (int j = 0; j < 8; ++j)
            out[m * DIM_ + n0 + tx * 8 + j] = acc[i][j] + bo[n0 + tx * 8 + j];
    }
}

// ---------------------------------------------------------------------------
extern "C" void kernel_launch(void* const* d_in, const int* in_sizes, int n_in,
                              void* d_out, int out_size, void* d_ws, size_t ws_size,
                              hipStream_t stream)
{
    const float* x  = (const float*)d_in[0];
    const float* st = (const float*)d_in[1];
    const float* Wq = (const float*)d_in[2];
    const float* bq = (const float*)d_in[3];
    const float* Wk = (const float*)d_in[4];
    const float* bk = (const float*)d_in[5];
    const float* Wv = (const float*)d_in[6];
    const float* bv = (const float*)d_in[7];
    const float* Wo = (const float*)d_in[8];
    const float* bo = (const float*)d_in[9];
    const float* lr = (const float*)d_in[10];

    float* out = (float*)d_out;
    float* Wf  = out + (size_t)B_ * S_ * DIM_;   // final state, after out

    float* qkv = (float*)d_ws;                   // [S][B][384]
    float* ys  = qkv + (size_t)S_ * B_ * 384;    // [S][B][128]

    dim3 gp(128, 3);
    proj_kernel<<<gp, 256, 0, stream>>>(x, Wq, bq, Wk, bk, Wv, bv, qkv);

    scan_kernel<<<128, 64, 0, stream>>>(qkv, st, lr, ys, Wf);

    dim3 go(128, 16);
    outproj_kernel<<<go, 256, 0, stream>>>(ys, Wo, bo, out);
}

// Round 2
// 927.613 us; speedup vs baseline: 1.4373x; 1.1451x over previous
//
#include <hip/hip_runtime.h>

#define B_ 8
#define S_ 2048
#define DIM_ 2048
#define HD_ 128

typedef __attribute__((ext_vector_type(2))) float f32x2;
typedef __attribute__((ext_vector_type(4))) float f32x4;

// ---------------------------------------------------------------------------
// packed-fp32 helpers. On CDNA4 the fp32 FLOP rate is the same packed or
// scalar (157 TF pipe); pk halves the ISSUE slots, freeing the wave to
// co-issue LDS/VMEM — that's the win in a GEMM inner loop.
// ---------------------------------------------------------------------------
static __device__ __forceinline__ void pkfma(f32x2& d, f32x2 a, f32x2 b) {
    asm("v_pk_fma_f32 %0, %1, %2, %0" : "+v"(d) : "v"(a), "v"(b));
}
static __device__ __forceinline__ void pkmul(f32x2& d, f32x2 a, f32x2 b) {
    asm("v_pk_mul_f32 %0, %1, %2" : "=v"(d) : "v"(a), "v"(b));
}
static __device__ __forceinline__ f32x2 pkadd(f32x2 a, f32x2 b) {
    f32x2 d;
    asm("v_pk_add_f32 %0, %1, %2" : "=v"(d) : "v"(a), "v"(b));
    return d;
}
// GEMM micro-kernel ops: d += broadcast(a.lo_or_hi) * b  via VOP3P op_sel.
// op_sel picks the src half feeding the LO result, op_sel_hi the HI result.
static __device__ __forceinline__ void pkfma_lo(f32x2& d, f32x2 a, f32x2 b) {
    asm("v_pk_fma_f32 %0, %1, %2, %0 op_sel:[0,0,0] op_sel_hi:[0,1,1]"
        : "+v"(d) : "v"(a), "v"(b));
}
static __device__ __forceinline__ void pkfma_hi(f32x2& d, f32x2 a, f32x2 b) {
    asm("v_pk_fma_f32 %0, %1, %2, %0 op_sel:[1,0,0] op_sel_hi:[1,1,1]"
        : "+v"(d) : "v"(a), "v"(b));
}

// ---------------------------------------------------------------------------
// all-VALU 8-lane butterfly reduction via DPP (no LDS pipe on critical path)
// ---------------------------------------------------------------------------
static __device__ __forceinline__ float xadd1(float x) {
    int o = __builtin_amdgcn_update_dpp(0, __float_as_int(x), 0xB1, 0xF, 0xF, true);
    return x + __int_as_float(o);
}
static __device__ __forceinline__ float xadd2(float x) {
    int o = __builtin_amdgcn_update_dpp(0, __float_as_int(x), 0x4E, 0xF, 0xF, true);
    return x + __int_as_float(o);
}
static __device__ __forceinline__ float xaddh(float x) {
    int o = __builtin_amdgcn_update_dpp(0, __float_as_int(x), 0x141, 0xF, 0xF, true);
    return x + __int_as_float(o);
}

// ---------------------------------------------------------------------------
// Projection GEMM: qkv[s][b][j*128+n] = x[(b,s),:] @ W_j + bias_j
// Round-2: 64x128 tile (grid 768 = 3 blocks/CU, was 1.5 — occupancy was
// grid-limited at 17.9%), pk_fma micro-kernel (half the VALU issue slots).
// ---------------------------------------------------------------------------
__global__ __launch_bounds__(256, 3) void proj_kernel(
    const float* __restrict__ x,
    const float* __restrict__ Wq, const float* __restrict__ bq,
    const float* __restrict__ Wk, const float* __restrict__ bk,
    const float* __restrict__ Wv, const float* __restrict__ bv,
    float* __restrict__ qkv)
{
    __shared__ __align__(16) float As[32][68];   // [k][m], 64 rows, pad->68
    __shared__ __align__(16) float Bs[32][132];  // [k][n], 128 cols

    const int jsel = blockIdx.y;
    const float* Wj   = (jsel == 0) ? Wq : (jsel == 1) ? Wk : Wv;
    const float* bias = (jsel == 0) ? bq : (jsel == 1) ? bk : bv;

    const int m0 = blockIdx.x * 64;
    const int t  = threadIdx.x;
    const int tx = t & 15;      // 8-col group
    const int ty = t >> 4;      // 0..15, 4 rows each

    f32x2 acc[4][4];
    #pragma unroll
    for (int i = 0; i < 4; ++i)
        #pragma unroll
        for (int j = 0; j < 4; ++j) { acc[i][j].x = 0.f; acc[i][j].y = 0.f; }

    for (int k0 = 0; k0 < DIM_; k0 += 32) {
        // A-tile: 64 rows x 32 k = 512 float4, 2 per thread (transposed store)
        #pragma unroll
        for (int p = 0; p < 2; ++p) {
            int slot = t + p * 256;
            int row  = slot >> 3;     // 0..63
            int c4   = slot & 7;
            float4 v = *(const float4*)&x[(size_t)(m0 + row) * DIM_ + k0 + c4 * 4];
            As[c4 * 4 + 0][row] = v.x;
            As[c4 * 4 + 1][row] = v.y;
            As[c4 * 4 + 2][row] = v.z;
            As[c4 * 4 + 3][row] = v.w;
        }
        // B-tile: 32 k x 128 n, 4 float4 per thread
        #pragma unroll
        for (int p = 0; p < 4; ++p) {
            int slot = t + p * 256;
            int kr   = slot >> 5;
            int n4   = slot & 31;
            *(float4*)&Bs[kr][n4 * 4] =
                *(const float4*)&Wj[(size_t)(k0 + kr) * HD_ + n4 * 4];
        }
        __syncthreads();

        #pragma unroll 8
        for (int kk = 0; kk < 32; ++kk) {
            f32x4 av = *(const f32x4*)&As[kk][ty * 4];
            f32x4 b0 = *(const f32x4*)&Bs[kk][tx * 8];
            f32x4 b1 = *(const f32x4*)&Bs[kk][tx * 8 + 4];
            f32x2 alo = av.xy, ahi = av.zw;
            f32x2 bp0 = b0.xy, bp1 = b0.zw, bp2 = b1.xy, bp3 = b1.zw;
            pkfma_lo(acc[0][0], alo, bp0); pkfma_lo(acc[0][1], alo, bp1);
            pkfma_lo(acc[0][2], alo, bp2); pkfma_lo(acc[0][3], alo, bp3);
            pkfma_hi(acc[1][0], alo, bp0); pkfma_hi(acc[1][1], alo, bp1);
            pkfma_hi(acc[1][2], alo, bp2); pkfma_hi(acc[1][3], alo, bp3);
            pkfma_lo(acc[2][0], ahi, bp0); pkfma_lo(acc[2][1], ahi, bp1);
            pkfma_lo(acc[2][2], ahi, bp2); pkfma_lo(acc[2][3], ahi, bp3);
            pkfma_hi(acc[3][0], ahi, bp0); pkfma_hi(acc[3][1], ahi, bp1);
            pkfma_hi(acc[3][2], ahi, bp2); pkfma_hi(acc[3][3], ahi, bp3);
        }
        __syncthreads();
    }

    float4 bv0 = *(const float4*)&bias[tx * 8];
    float4 bv1 = *(const float4*)&bias[tx * 8 + 4];
    #pragma unroll
    for (int i = 0; i < 4; ++i) {
        int m = m0 + ty * 4 + i;
        int bb = m >> 11;
        int ss = m & 2047;
        size_t base = ((size_t)ss * B_ + bb) * 384 + jsel * 128 + tx * 8;
        float4 o0, o1;
        o0.x = acc[i][0].x + bv0.x; o0.y = acc[i][0].y + bv0.y;
        o0.z = acc[i][1].x + bv0.z; o0.w = acc[i][1].y + bv0.w;
        o1.x = acc[i][2].x + bv1.x; o1.y = acc[i][2].y + bv1.y;
        o1.z = acc[i][3].x + bv1.z; o1.w = acc[i][3].y + bv1.w;
        *(float4*)&qkv[base]     = o0;
        *(float4*)&qkv[base + 4] = o1;
    }
}

// ---------------------------------------------------------------------------
// Row-parallel sequential scan, 4-deep asm pipeline with counted vmcnt.
// Round-2 change: the per-step [s_waitcnt; sched_barrier(0)] full fence is
// replaced by a waitcnt asm carrying DATA-DEPS on the slot's 9 registers.
// Volatile-volatile order keeps it after the loads; the deps pin the
// consumers (rule #18) WITHOUT fencing the scheduler — y-work of step s can
// now overlap the e-chain of step s+1 (previous fences serialized them:
// 380 cy/step measured vs ~120 cy chain+issue floor).
// vmcnt ledger unchanged: peel 27/28/29/30, steady 31, tail 31/22/13/4.
// ---------------------------------------------------------------------------
__global__ __launch_bounds__(64) void scan_kernel(
    const float* __restrict__ qkv,   // [S][B][384]
    const float* __restrict__ state, // [B][128][128]
    const float* __restrict__ lrp,
    float* __restrict__ ys,          // [S][B][128]
    float* __restrict__ Wf)          // [B][128][128]
{
    const int b    = blockIdx.x & 7;    // batch -> XCD b (L2 locality)
    const int g    = blockIdx.x >> 3;   // row group 0..15
    const int t    = threadIdx.x;
    const int row  = t >> 3;            // 0..7
    const int ch   = t & 7;             // col chunk (16 cols)
    const int grow = g * 8 + row;       // global row 0..127

    const float plr = lrp[0];
    const float nlr = -plr;

    f32x4 Qs0a, Qs0b, Qs0c, Qs0d, Ks0a, Ks0b, Ks0c, Ks0d;
    f32x4 Qs1a, Qs1b, Qs1c, Qs1d, Ks1a, Ks1b, Ks1c, Ks1d;
    f32x4 Qs2a, Qs2b, Qs2c, Qs2d, Ks2a, Ks2b, Ks2c, Ks2d;
    f32x4 Qs3a, Qs3b, Qs3c, Qs3d, Ks3a, Ks3b, Ks3c, Ks3d;
    float Vs0, Vs1, Vs2, Vs3;
    float ypcur;

    unsigned off  = (unsigned)((b * 384 + ch * 16) * 4);
    unsigned offV = (unsigned)((b * 384 + 256 + grow) * 4);
    unsigned offY = (unsigned)((b * HD_ + grow) * 4);
    unsigned offW = (unsigned)(((b * HD_ + grow) * HD_ + ch * 16) * 4);

    f32x4 wa, wb, wc, wd;
    asm volatile("global_load_dwordx4 %0, %1, %2"           : "=v"(wa) : "v"(offW), "s"(state));
    asm volatile("global_load_dwordx4 %0, %1, %2 offset:16" : "=v"(wb) : "v"(offW), "s"(state));
    asm volatile("global_load_dwordx4 %0, %1, %2 offset:32" : "=v"(wc) : "v"(offW), "s"(state));
    asm volatile("global_load_dwordx4 %0, %1, %2 offset:48" : "=v"(wd) : "v"(offW), "s"(state));

#define LOADSLOT(S) do {                                                                            \
        asm volatile("global_load_dwordx4 %0, %1, %2"            : "=v"(Qs##S##a) : "v"(off),  "s"(qkv)); \
        asm volatile("global_load_dwordx4 %0, %1, %2 offset:16"  : "=v"(Qs##S##b) : "v"(off),  "s"(qkv)); \
        asm volatile("global_load_dwordx4 %0, %1, %2 offset:32"  : "=v"(Qs##S##c) : "v"(off),  "s"(qkv)); \
        asm volatile("global_load_dwordx4 %0, %1, %2 offset:48"  : "=v"(Qs##S##d) : "v"(off),  "s"(qkv)); \
        asm volatile("global_load_dwordx4 %0, %1, %2 offset:512" : "=v"(Ks##S##a) : "v"(off),  "s"(qkv)); \
        asm volatile("global_load_dwordx4 %0, %1, %2 offset:528" : "=v"(Ks##S##b) : "v"(off),  "s"(qkv)); \
        asm volatile("global_load_dwordx4 %0, %1, %2 offset:544" : "=v"(Ks##S##c) : "v"(off),  "s"(qkv)); \
        asm volatile("global_load_dwordx4 %0, %1, %2 offset:560" : "=v"(Ks##S##d) : "v"(off),  "s"(qkv)); \
        asm volatile("global_load_dword %0, %1, %2"              : "=v"(Vs##S)    : "v"(offV), "s"(qkv)); \
        off  += 12288u;                                                                             \
        offV += 12288u;                                                                             \
    } while (0)

    LOADSLOT(0);
    LOADSLOT(1);
    LOADSLOT(2);
    LOADSLOT(3);

    asm volatile("s_waitcnt vmcnt(36)"
                 : "+v"(wa), "+v"(wb), "+v"(wc), "+v"(wd));
    f32x2 w01 = wa.xy, w23 = wa.zw, w45 = wb.xy, w67 = wb.zw;
    f32x2 w89 = wc.xy, wab = wc.zw, wcd = wd.xy, wef = wd.zw;

#define STEP(S, WCNT) do {                                                      \
        asm volatile("s_waitcnt vmcnt(" #WCNT ")"                               \
            : "+v"(Qs##S##a), "+v"(Qs##S##b), "+v"(Qs##S##c), "+v"(Qs##S##d),   \
              "+v"(Ks##S##a), "+v"(Ks##S##b), "+v"(Ks##S##c), "+v"(Ks##S##d),   \
              "+v"(Vs##S));                                                     \
        f32x2 ea, eb, ec, ed, ya, yb, yc, yd;                                   \
        pkmul(ea, w01, Ks##S##a.xy); pkmul(eb, w23, Ks##S##a.zw);               \
        pkmul(ec, w45, Ks##S##b.xy); pkmul(ed, w67, Ks##S##b.zw);               \
        pkfma(ea, w89, Ks##S##c.xy); pkfma(eb, wab, Ks##S##c.zw);               \
        pkfma(ec, wcd, Ks##S##d.xy); pkfma(ed, wef, Ks##S##d.zw);               \
        float lv = plr * Vs##S;              /* off critical path */            \
        f32x2 es = pkadd(pkadd(ea, eb), pkadd(ec, ed));                         \
        float ep = es.x + es.y;                                                 \
        ep = xadd1(ep); ep = xadd2(ep); ep = xaddh(ep);                         \
        float c = fmaf(nlr, ep, lv);         /* c = -lr*(ep - v) */             \
        f32x2 c2; c2.x = c; c2.y = c;                                           \
        pkmul(ya, w01, Qs##S##a.xy); pkmul(yb, w23, Qs##S##a.zw);               \
        pkmul(yc, w45, Qs##S##b.xy); pkmul(yd, w67, Qs##S##b.zw);               \
        pkfma(ya, w89, Qs##S##c.xy); pkfma(yb, wab, Qs##S##c.zw);               \
        pkfma(yc, wcd, Qs##S##d.xy); pkfma(yd, wef, Qs##S##d.zw);               \
        pkfma(w01, c2, Ks##S##a.xy); pkfma(w23, c2, Ks##S##a.zw);               \
        pkfma(w45, c2, Ks##S##b.xy); pkfma(w67, c2, Ks##S##b.zw);               \
        pkfma(w89, c2, Ks##S##c.xy); pkfma(wab, c2, Ks##S##c.zw);               \
        pkfma(wcd, c2, Ks##S##d.xy); pkfma(wef, c2, Ks##S##d.zw);               \
        f32x2 ysum = pkadd(pkadd(ya, yb), pkadd(yc, yd));                       \
        float yp = ysum.x + ysum.y;                                             \
        yp = xadd1(yp); yp = xadd2(yp); yp = xaddh(yp);                         \
        ypcur = yp;                                                             \
    } while (0)

#define YST() do {                                                              \
        if (ch == 0)                                                            \
            asm volatile("global_store_dword %0, %1, %2"                        \
                         :: "v"(offY), "v"(ypcur), "s"(ys));                    \
        offY += 4096u;                                                          \
    } while (0)

    // ---- peel: steps 0..3 ----
    STEP(0, 27); LOADSLOT(0); YST();
    STEP(1, 28); LOADSLOT(1); YST();
    STEP(2, 29); LOADSLOT(2); YST();
    STEP(3, 30); LOADSLOT(3); YST();

    // ---- steady state ----
    #pragma unroll 1
    for (int s = 4; s < S_ - 4; s += 4) {
        STEP(0, 31); LOADSLOT(0); YST();
        STEP(1, 31); LOADSLOT(1); YST();
        STEP(2, 31); LOADSLOT(2); YST();
        STEP(3, 31); LOADSLOT(3); YST();
    }

    // ---- tail: drain ----
    STEP(0, 31); YST();
    STEP(1, 22); YST();
    STEP(2, 13); YST();
    STEP(3, 4);  YST();

#undef LOADSLOT
#undef STEP
#undef YST

    {
        float* wdst = Wf + ((size_t)b * HD_ + grow) * HD_ + ch * 16;
        f32x4 o0, o1, o2, o3;
        o0.xy = w01; o0.zw = w23;
        o1.xy = w45; o1.zw = w67;
        o2.xy = w89; o2.zw = wab;
        o3.xy = wcd; o3.zw = wef;
        *(f32x4*)&wdst[0]  = o0;
        *(f32x4*)&wdst[4]  = o1;
        *(f32x4*)&wdst[8]  = o2;
        *(f32x4*)&wdst[12] = o3;
    }
}

// ---------------------------------------------------------------------------
// Output projection: out[(b,s), n] = ys[s][b][:] @ Wo + bo
// Round-2: K-tile 64->32 (LDS 67.6->33.8 KB => 2->4 blocks/CU), pk_fma
// micro-kernel, float4 epilogue stores (were 64 scalar global stores/thr).
// ---------------------------------------------------------------------------
__global__ __launch_bounds__(256, 4) void outproj_kernel(
    const float* __restrict__ ys,   // [S][B][128]
    const float* __restrict__ Wo,   // [128][2048]
    const float* __restrict__ bo,   // [2048]
    float* __restrict__ out)        // [B*S][2048]
{
    __shared__ __align__(16) float As[32][132];  // [k][m]
    __shared__ __align__(16) float Bs[32][132];  // [k][n]

    const int m0 = blockIdx.x * 128;
    const int n0 = blockIdx.y * 128;
    const int bb = m0 >> 11;
    const int s0 = m0 & 2047;
    const int t  = threadIdx.x;
    const int tx = t & 15;
    const int ty = t >> 4;

    f32x2 acc[8][4];
    #pragma unroll
    for (int i = 0; i < 8; ++i)
        #pragma unroll
        for (int j = 0; j < 4; ++j) { acc[i][j].x = 0.f; acc[i][j].y = 0.f; }

    for (int k0 = 0; k0 < HD_; k0 += 32) {
        #pragma unroll
        for (int p = 0; p < 4; ++p) {
            int slot = t + p * 256;
            int row  = slot >> 3;     // 0..127
            int c4   = slot & 7;
            float4 v = *(const float4*)&ys[((size_t)(s0 + row) * B_ + bb) * HD_ + k0 + c4 * 4];
            As[c4 * 4 + 0][row] = v.x;
            As[c4 * 4 + 1][row] = v.y;
            As[c4 * 4 + 2][row] = v.z;
            As[c4 * 4 + 3][row] = v.w;
        }
        #pragma unroll
        for (int p = 0; p < 4; ++p) {
            int slot = t + p * 256;
            int kr   = slot >> 5;
            int n4   = slot & 31;
            *(float4*)&Bs[kr][n4 * 4] =
                *(const float4*)&Wo[(size_t)(k0 + kr) * DIM_ + n0 + n4 * 4];
        }
        __syncthreads();

        #pragma unroll 8
        for (int kk = 0; kk < 32; ++kk) {
            f32x4 a0 = *(const f32x4*)&As[kk][ty * 8];
            f32x4 a1 = *(const f32x4*)&As[kk][ty * 8 + 4];
            f32x4 bv0 = *(const f32x4*)&Bs[kk][tx * 8];
            f32x4 bv1 = *(const f32x4*)&Bs[kk][tx * 8 + 4];
            f32x2 ap0 = a0.xy, ap1 = a0.zw, ap2 = a1.xy, ap3 = a1.zw;
            f32x2 bp0 = bv0.xy, bp1 = bv0.zw, bp2 = bv1.xy, bp3 = bv1.zw;
            pkfma_lo(acc[0][0], ap0, bp0); pkfma_lo(acc[0][1], ap0, bp1);
            pkfma_lo(acc[0][2], ap0, bp2); pkfma_lo(acc[0][3], ap0, bp3);
            pkfma_hi(acc[1][0], ap0, bp0); pkfma_hi(acc[1][1], ap0, bp1);
            pkfma_hi(acc[1][2], ap0, bp2); pkfma_hi(acc[1][3], ap0, bp3);
            pkfma_lo(acc[2][0], ap1, bp0); pkfma_lo(acc[2][1], ap1, bp1);
            pkfma_lo(acc[2][2], ap1, bp2); pkfma_lo(acc[2][3], ap1, bp3);
            pkfma_hi(acc[3][0], ap1, bp0); pkfma_hi(acc[3][1], ap1, bp1);
            pkfma_hi(acc[3][2], ap1, bp2); pkfma_hi(acc[3][3], ap1, bp3);
            pkfma_lo(acc[4][0], ap2, bp0); pkfma_lo(acc[4][1], ap2, bp1);
            pkfma_lo(acc[4][2], ap2, bp2); pkfma_lo(acc[4][3], ap2, bp3);
            pkfma_hi(acc[5][0], ap2, bp0); pkfma_hi(acc[5][1], ap2, bp1);
            pkfma_hi(acc[5][2], ap2, bp2); pkfma_hi(acc[5][3], ap2, bp3);
            pkfma_lo(acc[6][0], ap3, bp0); pkfma_lo(acc[6][1], ap3, bp1);
            pkfma_lo(acc[6][2], ap3, bp2); pkfma_lo(acc[6][3], ap3, bp3);
            pkfma_hi(acc[7][0], ap3, bp0); pkfma_hi(acc[7][1], ap3, bp1);
            pkfma_hi(acc[7][2], ap3, bp2); pkfma_hi(acc[7][3], ap3, bp3);
        }
        __syncthreads();
    }

    float4 bo0 = *(const float4*)&bo[n0 + tx * 8];
    float4 bo1 = *(const float4*)&bo[n0 + tx * 8 + 4];
    #pragma unroll
    for (int i = 0; i < 8; ++i) {
        size_t m = m0 + ty * 8 + i;
        float4 o0, o1;
        o0.x = acc[i][0].x + bo0.x; o0.y = acc[i][0].y + bo0.y;
        o0.z = acc[i][1].x + bo0.z; o0.w = acc[i][1].y + bo0.w;
        o1.x = acc[i][2].x + bo1.x; o1.y = acc[i][2].y + bo1.y;
        o1.z = acc[i][3].x + bo1.z; o1.w = acc[i][3].y + bo1.w;
        *(float4*)&out[m * DIM_ + n0 + tx * 8]     = o0;
        *(float4*)&out[m * DIM_ + n0 + tx * 8 + 4] = o1;
    }
}

// ---------------------------------------------------------------------------
extern "C" void kernel_launch(void* const* d_in, const int* in_sizes, int n_in,
                              void* d_out, int out_size, void* d_ws, size_t ws_size,
                              hipStream_t stream)
{
    const float* x  = (const float*)d_in[0];
    const float* st = (const float*)d_in[1];
    const float* Wq = (const float*)d_in[2];
    const float* bq = (const float*)d_in[3];
    const float* Wk = (const float*)d_in[4];
    const float* bk = (const float*)d_in[5];
    const float* Wv = (const float*)d_in[6];
    const float* bv = (const float*)d_in[7];
    const float* Wo = (const float*)d_in[8];
    const float* bo = (const float*)d_in[9];
    const float* lr = (const float*)d_in[10];

    float* out = (float*)d_out;
    float* Wf  = out + (size_t)B_ * S_ * DIM_;   // final state, after out

    float* qkv = (float*)d_ws;                   // [S][B][384]
    float* ys  = qkv + (size_t)S_ * B_ * 384;    // [S][B][128]

    dim3 gp(256, 3);
    proj_kernel<<<gp, 256, 0, stream>>>(x, Wq, bq, Wk, bk, Wv, bv, qkv);

    scan_kernel<<<128, 64, 0, stream>>>(qkv, st, lr, ys, Wf);

    dim3 go(128, 16);
    outproj_kernel<<<go, 256, 0, stream>>>(ys, Wo, bo, out);
}

// Round 3
// 674.459 us; speedup vs baseline: 1.9768x; 1.3753x over previous
//
#include <hip/hip_runtime.h>

#define B_ 8
#define S_ 2048
#define DIM_ 2048
#define HD_ 128

typedef __attribute__((ext_vector_type(2))) float f32x2;
typedef __attribute__((ext_vector_type(4))) float f32x4;
typedef __attribute__((ext_vector_type(8))) short bf16x8;   // 8 bf16 in 4 VGPRs
typedef __attribute__((ext_vector_type(4))) unsigned short us4;

// ---------------------------------------------------------------------------
// packed-fp32 helpers (scan kernel)
// ---------------------------------------------------------------------------
static __device__ __forceinline__ void pkfma(f32x2& d, f32x2 a, f32x2 b) {
    asm("v_pk_fma_f32 %0, %1, %2, %0" : "+v"(d) : "v"(a), "v"(b));
}
static __device__ __forceinline__ void pkmul(f32x2& d, f32x2 a, f32x2 b) {
    asm("v_pk_mul_f32 %0, %1, %2" : "=v"(d) : "v"(a), "v"(b));
}
static __device__ __forceinline__ f32x2 pkadd(f32x2 a, f32x2 b) {
    f32x2 d;
    asm("v_pk_add_f32 %0, %1, %2" : "=v"(d) : "v"(a), "v"(b));
    return d;
}
// all-VALU 8-lane butterfly reduction via DPP
static __device__ __forceinline__ float xadd1(float x) {
    int o = __builtin_amdgcn_update_dpp(0, __float_as_int(x), 0xB1, 0xF, 0xF, true);
    return x + __int_as_float(o);
}
static __device__ __forceinline__ float xadd2(float x) {
    int o = __builtin_amdgcn_update_dpp(0, __float_as_int(x), 0x4E, 0xF, 0xF, true);
    return x + __int_as_float(o);
}
static __device__ __forceinline__ float xaddh(float x) {
    int o = __builtin_amdgcn_update_dpp(0, __float_as_int(x), 0x141, 0xF, 0xF, true);
    return x + __int_as_float(o);
}

// ---------------------------------------------------------------------------
// bf16 split helpers: v = hi + lo with hi = RNE-bf16(v), lo = RNE-bf16(v-hi).
// Residual ~2^-18 relative; dropped lo*lo term in the GEMM ~2^-34.
// ---------------------------------------------------------------------------
static __device__ __forceinline__ unsigned short bf16_rne(float f) {
    unsigned u = __float_as_uint(f);
    unsigned r = (u + 0x7FFFu + ((u >> 16) & 1u)) >> 16;
    return (unsigned short)r;
}
static __device__ __forceinline__ void split_bf16(float v, unsigned short& h, unsigned short& l) {
    h = bf16_rne(v);
    float hf = __uint_as_float(((unsigned)h) << 16);
    l = bf16_rne(v - hf);
}

// ---------------------------------------------------------------------------
// Pre-convert: Wq|Wk|Wv [2048][128] -> wht/wtl [384][2048] bf16 (TRANSPOSED,
// so the GEMM's B-fragment reads 8 contiguous k per lane). 786432 threads.
// ---------------------------------------------------------------------------
__global__ __launch_bounds__(256) void convert_w(
    const float* __restrict__ Wq, const float* __restrict__ Wk,
    const float* __restrict__ Wv,
    unsigned short* __restrict__ wht, unsigned short* __restrict__ wtl)
{
    int i = blockIdx.x * 256 + threadIdx.x;          // [0, 786432)
    int jsel = i >> 18;                              // 0..2
    int r    = i & 262143;
    int k    = r >> 7;
    int nn   = r & 127;
    const float* W = (jsel == 0) ? Wq : (jsel == 1) ? Wk : Wv;
    float v = W[(size_t)k * 128 + nn];               // coalesced over nn
    unsigned short h, l;
    split_bf16(v, h, l);
    size_t dst = (size_t)(jsel * 128 + nn) * 2048 + k;
    wht[dst] = h;
    wtl[dst] = l;
}

// ---------------------------------------------------------------------------
// Post-scan convert: ys [16384][128] f32 -> ysh/ysl bf16 planes, and
// Wo [128][2048] -> woth/wotl [2048][128] (transposed). 786432 threads.
// ---------------------------------------------------------------------------
__global__ __launch_bounds__(256) void convert_post(
    const float* __restrict__ ys, const float* __restrict__ Wo,
    unsigned short* __restrict__ ysh, unsigned short* __restrict__ ysl,
    unsigned short* __restrict__ woth, unsigned short* __restrict__ wotl)
{
    int tid = blockIdx.x * 256 + threadIdx.x;
    if (tid < 524288) {                              // ys part: f32x4 each
        f32x4 v = *(const f32x4*)&ys[(size_t)tid * 4];
        us4 h, l;
        #pragma unroll
        for (int i = 0; i < 4; ++i) {
            unsigned short hh, ll;
            split_bf16(v[i], hh, ll);
            h[i] = hh; l[i] = ll;
        }
        *(us4*)&ysh[(size_t)tid * 4] = h;
        *(us4*)&ysl[(size_t)tid * 4] = l;
    } else {                                         // Wo part: scalar
        int t2 = tid - 524288;                       // [0, 262144)
        int k = t2 >> 11;
        int n = t2 & 2047;
        float v = Wo[t2];                            // coalesced over n
        unsigned short h, l;
        split_bf16(v, h, l);
        size_t dst = (size_t)n * 128 + k;
        woth[dst] = h;
        wotl[dst] = l;
    }
}

// ---------------------------------------------------------------------------
// Projection GEMM via bf16-split MFMA.
// C[16384][384] = X[16384][2048] @ Wcat[2048][384]; tile 64m x 128n, BK=32.
// X converted fp32->bf16(hi,lo) inline during staging; B pre-transposed.
// LDS tiles row-major with byte ^= (row&7)<<4 swizzle (conflict-free for
// both the staging writes and the stride-64B fragment reads — derived).
// MFMA 16x16x32_bf16: A row=lane&15, k=(lane>>4)*8+j; B col=lane&15, same k;
// D col=lane&15, row=(lane>>4)*4+reg [measured m89/m91].
// 3 MFMA per (hi,lo) pair: Ah*Bh + Al*Bh + Ah*Bl.
// ---------------------------------------------------------------------------
__global__ __launch_bounds__(256) void proj_mfma(
    const float* __restrict__ x,
    const unsigned short* __restrict__ wht, const unsigned short* __restrict__ wtl,
    const float* __restrict__ bq, const float* __restrict__ bk,
    const float* __restrict__ bv,
    float* __restrict__ qkv)
{
    __shared__ __align__(16) unsigned short Ah[64 * 32];   // 4 KB
    __shared__ __align__(16) unsigned short Al[64 * 32];
    __shared__ __align__(16) unsigned short Bh[128 * 32];  // 8 KB
    __shared__ __align__(16) unsigned short Bl[128 * 32];

    const int jsel = blockIdx.y;
    const float* bias = (jsel == 0) ? bq : (jsel == 1) ? bk : bv;
    const int m0  = blockIdx.x * 64;
    const int n0g = jsel * 128;                 // row offset into wht/wtl
    const int t    = threadIdx.x;
    const int lane = t & 63;
    const int wid  = t >> 6;                    // n-quadrant 0..3 (32 cols each)
    const int fr   = lane & 15;
    const int hi   = lane >> 4;

    f32x4 acc[4][2];
    #pragma unroll
    for (int i = 0; i < 4; ++i)
        #pragma unroll
        for (int j = 0; j < 2; ++j) acc[i][j] = (f32x4){0.f, 0.f, 0.f, 0.f};

    for (int k0 = 0; k0 < DIM_; k0 += 32) {
        // ---- stage A: 64 rows x 32 k fp32 -> bf16 hi/lo (inline convert) ----
        #pragma unroll
        for (int p = 0; p < 2; ++p) {
            int u   = t + p * 256;              // 0..511
            int row = u >> 3;                   // 0..63
            int c   = u & 7;                    // f32x4 unit in row
            f32x4 v = *(const f32x4*)&x[(size_t)(m0 + row) * DIM_ + k0 + c * 4];
            us4 hv, lv;
            #pragma unroll
            for (int i = 0; i < 4; ++i) {
                unsigned short hh, ll;
                split_bf16(v[i], hh, ll);
                hv[i] = hh; lv[i] = ll;
            }
            unsigned byte = (unsigned)(row * 64 + c * 8) ^ ((unsigned)(row & 7) << 4);
            *(us4*)((char*)Ah + byte) = hv;
            *(us4*)((char*)Al + byte) = lv;
        }
        // ---- stage B: 128 rows x 32 k bf16 (pre-converted, transposed) ----
        #pragma unroll
        for (int p = 0; p < 2; ++p) {
            int u   = t + p * 256;              // 0..511
            int row = u >> 2;                   // 0..127
            int uc  = u & 3;                    // 16B unit in row
            size_t src = (size_t)(n0g + row) * 2048 + k0 + uc * 8;
            bf16x8 hv = *(const bf16x8*)&wht[src];
            bf16x8 lv = *(const bf16x8*)&wtl[src];
            unsigned byte = (unsigned)(row * 64 + uc * 16) ^ ((unsigned)(row & 7) << 4);
            *(bf16x8*)((char*)Bh + byte) = hv;
            *(bf16x8*)((char*)Bl + byte) = lv;
        }
        __syncthreads();

        // ---- fragments ----
        bf16x8 ah[4], al[4], bh[2], bl[2];
        #pragma unroll
        for (int mt = 0; mt < 4; ++mt) {
            int row = mt * 16 + fr;
            unsigned byte = (unsigned)(row * 64 + hi * 16) ^ ((unsigned)(row & 7) << 4);
            ah[mt] = *(const bf16x8*)((const char*)Ah + byte);
            al[mt] = *(const bf16x8*)((const char*)Al + byte);
        }
        #pragma unroll
        for (int nt = 0; nt < 2; ++nt) {
            int row = wid * 32 + nt * 16 + fr;
            unsigned byte = (unsigned)(row * 64 + hi * 16) ^ ((unsigned)(row & 7) << 4);
            bh[nt] = *(const bf16x8*)((const char*)Bh + byte);
            bl[nt] = *(const bf16x8*)((const char*)Bl + byte);
        }
        // ---- 24 MFMA: hi*hi + lo*hi + hi*lo ----
        #pragma unroll
        for (int mt = 0; mt < 4; ++mt)
            #pragma unroll
            for (int nt = 0; nt < 2; ++nt) {
                acc[mt][nt] = __builtin_amdgcn_mfma_f32_16x16x32_bf16(ah[mt], bh[nt], acc[mt][nt], 0, 0, 0);
                acc[mt][nt] = __builtin_amdgcn_mfma_f32_16x16x32_bf16(al[mt], bh[nt], acc[mt][nt], 0, 0, 0);
                acc[mt][nt] = __builtin_amdgcn_mfma_f32_16x16x32_bf16(ah[mt], bl[nt], acc[mt][nt], 0, 0, 0);
            }
        __syncthreads();
    }

    // ---- epilogue: D col=lane&15, row=(lane>>4)*4+r ----
    #pragma unroll
    for (int nt = 0; nt < 2; ++nt) {
        int nl = wid * 32 + nt * 16 + fr;       // 0..127
        float bsum = bias[nl];
        #pragma unroll
        for (int mt = 0; mt < 4; ++mt)
            #pragma unroll
            for (int r = 0; r < 4; ++r) {
                int m  = m0 + mt * 16 + hi * 4 + r;
                int bb = m >> 11;
                int ss = m & 2047;
                qkv[((size_t)ss * B_ + bb) * 384 + jsel * 128 + nl] = acc[mt][nt][r] + bsum;
            }
    }
}

// ---------------------------------------------------------------------------
// Output projection via bf16-split MFMA.
// out[(b,s)][2048] = ys[(s,b)][128] @ Wo[128][2048]; tile 128m x 128n, BK=32.
// A = ysh/ysl [m'=s*8+b][128]; B = woth/wotl [2048][128] (pre-transposed).
// ---------------------------------------------------------------------------
__global__ __launch_bounds__(256) void outproj_mfma(
    const unsigned short* __restrict__ ysh, const unsigned short* __restrict__ ysl,
    const unsigned short* __restrict__ woth, const unsigned short* __restrict__ wotl,
    const float* __restrict__ bo,
    float* __restrict__ out)
{
    __shared__ __align__(16) unsigned short Ah[128 * 32];  // 8 KB each
    __shared__ __align__(16) unsigned short Al[128 * 32];
    __shared__ __align__(16) unsigned short Bh[128 * 32];
    __shared__ __align__(16) unsigned short Bl[128 * 32];

    const int m0 = blockIdx.x * 128;            // m' = s*8+b
    const int n0 = blockIdx.y * 128;
    const int t    = threadIdx.x;
    const int lane = t & 63;
    const int wid  = t >> 6;
    const int wm   = wid >> 1;                  // 2x2 wave grid, 64x64 each
    const int wn   = wid & 1;
    const int fr   = lane & 15;
    const int hi   = lane >> 4;

    f32x4 acc[4][4];
    #pragma unroll
    for (int i = 0; i < 4; ++i)
        #pragma unroll
        for (int j = 0; j < 4; ++j) acc[i][j] = (f32x4){0.f, 0.f, 0.f, 0.f};

    #pragma unroll 1
    for (int k0 = 0; k0 < HD_; k0 += 32) {
        #pragma unroll
        for (int p = 0; p < 2; ++p) {
            int u   = t + p * 256;              // 0..511
            int row = u >> 2;                   // 0..127
            int uc  = u & 3;
            unsigned byte = (unsigned)(row * 64 + uc * 16) ^ ((unsigned)(row & 7) << 4);
            size_t asrc = (size_t)(m0 + row) * HD_ + k0 + uc * 8;
            *(bf16x8*)((char*)Ah + byte) = *(const bf16x8*)&ysh[asrc];
            *(bf16x8*)((char*)Al + byte) = *(const bf16x8*)&ysl[asrc];
            size_t bsrc = (size_t)(n0 + row) * HD_ + k0 + uc * 8;
            *(bf16x8*)((char*)Bh + byte) = *(const bf16x8*)&woth[bsrc];
            *(bf16x8*)((char*)Bl + byte) = *(const bf16x8*)&wotl[bsrc];
        }
        __syncthreads();

        bf16x8 ah[4], al[4], bh[4], bl[4];
        #pragma unroll
        for (int mt = 0; mt < 4; ++mt) {
            int row = wm * 64 + mt * 16 + fr;
            unsigned byte = (unsigned)(row * 64 + hi * 16) ^ ((unsigned)(row & 7) << 4);
            ah[mt] = *(const bf16x8*)((const char*)Ah + byte);
            al[mt] = *(const bf16x8*)((const char*)Al + byte);
        }
        #pragma unroll
        for (int nt = 0; nt < 4; ++nt) {
            int row = wn * 64 + nt * 16 + fr;
            unsigned byte = (unsigned)(row * 64 + hi * 16) ^ ((unsigned)(row & 7) << 4);
            bh[nt] = *(const bf16x8*)((const char*)Bh + byte);
            bl[nt] = *(const bf16x8*)((const char*)Bl + byte);
        }
        #pragma unroll
        for (int mt = 0; mt < 4; ++mt)
            #pragma unroll
            for (int nt = 0; nt < 4; ++nt) {
                acc[mt][nt] = __builtin_amdgcn_mfma_f32_16x16x32_bf16(ah[mt], bh[nt], acc[mt][nt], 0, 0, 0);
                acc[mt][nt] = __builtin_amdgcn_mfma_f32_16x16x32_bf16(al[mt], bh[nt], acc[mt][nt], 0, 0, 0);
                acc[mt][nt] = __builtin_amdgcn_mfma_f32_16x16x32_bf16(ah[mt], bl[nt], acc[mt][nt], 0, 0, 0);
            }
        __syncthreads();
    }

    #pragma unroll
    for (int nt = 0; nt < 4; ++nt) {
        int nl = wn * 64 + nt * 16 + fr;
        float bsum = bo[n0 + nl];
        #pragma unroll
        for (int mt = 0; mt < 4; ++mt)
            #pragma unroll
            for (int r = 0; r < 4; ++r) {
                int mp = m0 + wm * 64 + mt * 16 + hi * 4 + r;   // m' = s*8+b
                int ss = mp >> 3;
                int bb = mp & 7;
                out[((size_t)bb * S_ + ss) * DIM_ + n0 + nl] = acc[mt][nt][r] + bsum;
            }
    }
}

// ---------------------------------------------------------------------------
// Row-parallel sequential scan — UNCHANGED from round 2 (isolate MFMA risk).
// ---------------------------------------------------------------------------
__global__ __launch_bounds__(64) void scan_kernel(
    const float* __restrict__ qkv,   // [S][B][384]
    const float* __restrict__ state, // [B][128][128]
    const float* __restrict__ lrp,
    float* __restrict__ ys,          // [S][B][128]
    float* __restrict__ Wf)          // [B][128][128]
{
    const int b    = blockIdx.x & 7;
    const int g    = blockIdx.x >> 3;
    const int t    = threadIdx.x;
    const int row  = t >> 3;
    const int ch   = t & 7;
    const int grow = g * 8 + row;

    const float plr = lrp[0];
    const float nlr = -plr;

    f32x4 Qs0a, Qs0b, Qs0c, Qs0d, Ks0a, Ks0b, Ks0c, Ks0d;
    f32x4 Qs1a, Qs1b, Qs1c, Qs1d, Ks1a, Ks1b, Ks1c, Ks1d;
    f32x4 Qs2a, Qs2b, Qs2c, Qs2d, Ks2a, Ks2b, Ks2c, Ks2d;
    f32x4 Qs3a, Qs3b, Qs3c, Qs3d, Ks3a, Ks3b, Ks3c, Ks3d;
    float Vs0, Vs1, Vs2, Vs3;
    float ypcur;

    unsigned off  = (unsigned)((b * 384 + ch * 16) * 4);
    unsigned offV = (unsigned)((b * 384 + 256 + grow) * 4);
    unsigned offY = (unsigned)((b * HD_ + grow) * 4);
    unsigned offW = (unsigned)(((b * HD_ + grow) * HD_ + ch * 16) * 4);

    f32x4 wa, wb, wc, wd;
    asm volatile("global_load_dwordx4 %0, %1, %2"           : "=v"(wa) : "v"(offW), "s"(state));
    asm volatile("global_load_dwordx4 %0, %1, %2 offset:16" : "=v"(wb) : "v"(offW), "s"(state));
    asm volatile("global_load_dwordx4 %0, %1, %2 offset:32" : "=v"(wc) : "v"(offW), "s"(state));
    asm volatile("global_load_dwordx4 %0, %1, %2 offset:48" : "=v"(wd) : "v"(offW), "s"(state));

#define LOADSLOT(S) do {                                                                            \
        asm volatile("global_load_dwordx4 %0, %1, %2"            : "=v"(Qs##S##a) : "v"(off),  "s"(qkv)); \
        asm volatile("global_load_dwordx4 %0, %1, %2 offset:16"  : "=v"(Qs##S##b) : "v"(off),  "s"(qkv)); \
        asm volatile("global_load_dwordx4 %0, %1, %2 offset:32"  : "=v"(Qs##S##c) : "v"(off),  "s"(qkv)); \
        asm volatile("global_load_dwordx4 %0, %1, %2 offset:48"  : "=v"(Qs##S##d) : "v"(off),  "s"(qkv)); \
        asm volatile("global_load_dwordx4 %0, %1, %2 offset:512" : "=v"(Ks##S##a) : "v"(off),  "s"(qkv)); \
        asm volatile("global_load_dwordx4 %0, %1, %2 offset:528" : "=v"(Ks##S##b) : "v"(off),  "s"(qkv)); \
        asm volatile("global_load_dwordx4 %0, %1, %2 offset:544" : "=v"(Ks##S##c) : "v"(off),  "s"(qkv)); \
        asm volatile("global_load_dwordx4 %0, %1, %2 offset:560" : "=v"(Ks##S##d) : "v"(off),  "s"(qkv)); \
        asm volatile("global_load_dword %0, %1, %2"              : "=v"(Vs##S)    : "v"(offV), "s"(qkv)); \
        off  += 12288u;                                                                             \
        offV += 12288u;                                                                             \
    } while (0)

    LOADSLOT(0);
    LOADSLOT(1);
    LOADSLOT(2);
    LOADSLOT(3);

    asm volatile("s_waitcnt vmcnt(36)"
                 : "+v"(wa), "+v"(wb), "+v"(wc), "+v"(wd));
    f32x2 w01 = wa.xy, w23 = wa.zw, w45 = wb.xy, w67 = wb.zw;
    f32x2 w89 = wc.xy, wab = wc.zw, wcd = wd.xy, wef = wd.zw;

#define STEP(S, WCNT) do {                                                      \
        asm volatile("s_waitcnt vmcnt(" #WCNT ")"                               \
            : "+v"(Qs##S##a), "+v"(Qs##S##b), "+v"(Qs##S##c), "+v"(Qs##S##d),   \
              "+v"(Ks##S##a), "+v"(Ks##S##b), "+v"(Ks##S##c), "+v"(Ks##S##d),   \
              "+v"(Vs##S));                                                     \
        f32x2 ea, eb, ec, ed, ya, yb, yc, yd;                                   \
        pkmul(ea, w01, Ks##S##a.xy); pkmul(eb, w23, Ks##S##a.zw);               \
        pkmul(ec, w45, Ks##S##b.xy); pkmul(ed, w67, Ks##S##b.zw);               \
        pkfma(ea, w89, Ks##S##c.xy); pkfma(eb, wab, Ks##S##c.zw);               \
        pkfma(ec, wcd, Ks##S##d.xy); pkfma(ed, wef, Ks##S##d.zw);               \
        float lv = plr * Vs##S;                                                 \
        f32x2 es = pkadd(pkadd(ea, eb), pkadd(ec, ed));                         \
        float ep = es.x + es.y;                                                 \
        ep = xadd1(ep); ep = xadd2(ep); ep = xaddh(ep);                         \
        float c = fmaf(nlr, ep, lv);                                            \
        f32x2 c2; c2.x = c; c2.y = c;                                           \
        pkmul(ya, w01, Qs##S##a.xy); pkmul(yb, w23, Qs##S##a.zw);               \
        pkmul(yc, w45, Qs##S##b.xy); pkmul(yd, w67, Qs##S##b.zw);               \
        pkfma(ya, w89, Qs##S##c.xy); pkfma(yb, wab, Qs##S##c.zw);               \
        pkfma(yc, wcd, Qs##S##d.xy); pkfma(yd, wef, Qs##S##d.zw);               \
        pkfma(w01, c2, Ks##S##a.xy); pkfma(w23, c2, Ks##S##a.zw);               \
        pkfma(w45, c2, Ks##S##b.xy); pkfma(w67, c2, Ks##S##b.zw);               \
        pkfma(w89, c2, Ks##S##c.xy); pkfma(wab, c2, Ks##S##c.zw);               \
        pkfma(wcd, c2, Ks##S##d.xy); pkfma(wef, c2, Ks##S##d.zw);               \
        f32x2 ysum = pkadd(pkadd(ya, yb), pkadd(yc, yd));                       \
        float yp = ysum.x + ysum.y;                                             \
        yp = xadd1(yp); yp = xadd2(yp); yp = xaddh(yp);                         \
        ypcur = yp;                                                             \
    } while (0)

#define YST() do {                                                              \
        if (ch == 0)                                                            \
            asm volatile("global_store_dword %0, %1, %2"                        \
                         :: "v"(offY), "v"(ypcur), "s"(ys));                    \
        offY += 4096u;                                                          \
    } while (0)

    STEP(0, 27); LOADSLOT(0); YST();
    STEP(1, 28); LOADSLOT(1); YST();
    STEP(2, 29); LOADSLOT(2); YST();
    STEP(3, 30); LOADSLOT(3); YST();

    #pragma unroll 1
    for (int s = 4; s < S_ - 4; s += 4) {
        STEP(0, 31); LOADSLOT(0); YST();
        STEP(1, 31); LOADSLOT(1); YST();
        STEP(2, 31); LOADSLOT(2); YST();
        STEP(3, 31); LOADSLOT(3); YST();
    }

    STEP(0, 31); YST();
    STEP(1, 22); YST();
    STEP(2, 13); YST();
    STEP(3, 4);  YST();

#undef LOADSLOT
#undef STEP
#undef YST

    {
        float* wdst = Wf + ((size_t)b * HD_ + grow) * HD_ + ch * 16;
        f32x4 o0, o1, o2, o3;
        o0.xy = w01; o0.zw = w23;
        o1.xy = w45; o1.zw = w67;
        o2.xy = w89; o2.zw = wab;
        o3.xy = wcd; o3.zw = wef;
        *(f32x4*)&wdst[0]  = o0;
        *(f32x4*)&wdst[4]  = o1;
        *(f32x4*)&wdst[8]  = o2;
        *(f32x4*)&wdst[12] = o3;
    }
}

// ---------------------------------------------------------------------------
// Workspace overlay (fits the previous session's exact 33,554,432 B budget):
//   seg0 [0, 25165824): qkv (live: proj->scan). After scan: ysh/ysl (8.4 MB)
//                       + woth/wotl (1.05 MB) aliased here.
//   seg1 [25165824, 33554432): wht/wtl during proj (3.15 MB, ys not yet
//                       written), then ys (live: scan->convert_post).
// ---------------------------------------------------------------------------
extern "C" void kernel_launch(void* const* d_in, const int* in_sizes, int n_in,
                              void* d_out, int out_size, void* d_ws, size_t ws_size,
                              hipStream_t stream)
{
    const float* x  = (const float*)d_in[0];
    const float* st = (const float*)d_in[1];
    const float* Wq = (const float*)d_in[2];
    const float* bq = (const float*)d_in[3];
    const float* Wk = (const float*)d_in[4];
    const float* bk = (const float*)d_in[5];
    const float* Wv = (const float*)d_in[6];
    const float* bv = (const float*)d_in[7];
    const float* Wo = (const float*)d_in[8];
    const float* bo = (const float*)d_in[9];
    const float* lr = (const float*)d_in[10];

    float* out = (float*)d_out;
    float* Wf  = out + (size_t)B_ * S_ * DIM_;

    char* ws = (char*)d_ws;
    float* qkv = (float*)ws;                               // 25,165,824 B
    float* ys  = (float*)(ws + 25165824);                  //  8,388,608 B
    // wht/wtl alias the ys region (dead until scan writes it)
    unsigned short* wht = (unsigned short*)(ws + 25165824);            // 1,572,864 B
    unsigned short* wtl = wht + 786432;                                // 1,572,864 B
    // ysh/ysl + woth/wotl alias the qkv region (dead after scan)
    unsigned short* ysh  = (unsigned short*)ws;                        // 4,194,304 B
    unsigned short* ysl  = ysh + 2097152;                              // 4,194,304 B
    unsigned short* woth = ysl + 2097152;                              //   524,288 B
    unsigned short* wotl = woth + 262144;                              //   524,288 B

    // 1. W -> bf16 hi/lo, transposed [384][2048]
    convert_w<<<3072, 256, 0, stream>>>(Wq, Wk, Wv, wht, wtl);

    // 2. projections (x converted inline)
    dim3 gp(256, 3);
    proj_mfma<<<gp, 256, 0, stream>>>(x, wht, wtl, bq, bk, bv, qkv);

    // 3. sequential scan (unchanged)
    scan_kernel<<<128, 64, 0, stream>>>(qkv, st, lr, ys, Wf);

    // 4. ys -> bf16 planes; Wo -> bf16 hi/lo transposed [2048][128]
    convert_post<<<3072, 256, 0, stream>>>(ys, Wo, ysh, ysl, woth, wotl);

    // 5. output projection
    dim3 go(128, 16);
    outproj_mfma<<<go, 256, 0, stream>>>(ysh, ysl, woth, wotl, bo, out);
}